// Round 16
// baseline (486.575 us; speedup 1.0000x reference)
//
#include <hip/hip_runtime.h>
#include <hip/hip_bf16.h>

#define N_IN 512
#define HID 32
#define OUTD 40
#define NCOPY 16  // 2 copies per XCD: same L2 locality, half the same-line atomic collisions

typedef __attribute__((ext_vector_type(8))) short bf16x8;
typedef __attribute__((ext_vector_type(4))) float f32x4;
typedef __attribute__((ext_vector_type(8))) _Float16 half8;

// ---------------- init: cnt8 zero + zero rows g1[n], p[n] ----------------

__global__ void k_init(int* __restrict__ cnt8, int n8_4, int n,
                       _Float16* __restrict__ g1, _Float16* __restrict__ p)
{
    int i = blockIdx.x * blockDim.x + threadIdx.x;
    if (i < n8_4) {
        int4 z4 = make_int4(0, 0, 0, 0);
        *(int4*)&cnt8[(size_t)i * 4] = z4;
    }
    if (blockIdx.x == 0) {
        float4 z = make_float4(0.f, 0.f, 0.f, 0.f);
        if (threadIdx.x < 4)
            ((float4*)&g1[(size_t)n * HID])[threadIdx.x] = z;       // 64B zero row
        else if (threadIdx.x < 8)
            ((float4*)&p[(size_t)n * HID])[threadIdx.x - 4] = z;    // 64B zero row
    }
}

// count into per-XCD copy; emit packed (copy<<24)|rank per edge (rank <= e < 2^24)
__global__ void k_count(const int* __restrict__ dst, int* __restrict__ cnt8,
                        int* __restrict__ rankp, int n, int e)
{
    int c = blockIdx.x & (NCOPY - 1);
    int* mycnt = cnt8 + (size_t)c * n;
    int i = (blockIdx.x * blockDim.x + threadIdx.x) * 4;
    if (i + 3 < e) {
        int4 d4 = *(const int4*)&dst[i];
        int r0 = atomicAdd(&mycnt[d4.x], 1);
        int r1 = atomicAdd(&mycnt[d4.y], 1);
        int r2 = atomicAdd(&mycnt[d4.z], 1);
        int r3 = atomicAdd(&mycnt[d4.w], 1);
        int hc = c << 24;
        *(int4*)&rankp[i] = make_int4(hc | r0, hc | r1, hc | r2, hc | r3);
    } else if (i < e) {
        for (int k = i; k < e; k++) {
            int r = atomicAdd(&mycnt[dst[k]], 1);
            rankp[k] = (c << 24) | r;
        }
    }
}

// fused: per-node prefix over the NCOPY copies (bases, in place) + cnt + dinv +
// block-local exclusive scan of EXACT degrees (1024 nodes/block)
__global__ __launch_bounds__(256) void k_scanA(int* __restrict__ cnt8,
                                               int* __restrict__ cnt,
                                               float* __restrict__ dinv,
                                               int* __restrict__ offs,
                                               int* __restrict__ bsums, int n)
{
    __shared__ int sm[256];
    int t = threadIdx.x;
    int base = blockIdx.x * 1024 + t * 4;
    int4 run = make_int4(0, 0, 0, 0);
    if (base < n) {  // n % 4 == 0: all 4 valid together
#pragma unroll
        for (int c = 0; c < NCOPY; c++) {
            int4 v = *(int4*)&cnt8[(size_t)c * n + base];
            *(int4*)&cnt8[(size_t)c * n + base] = run;  // exclusive base for copy c
            run.x += v.x; run.y += v.y; run.z += v.z; run.w += v.w;
        }
        *(int4*)&cnt[base] = run;
        float4 dv;
        dv.x = rsqrtf((float)(run.x + 1));
        dv.y = rsqrtf((float)(run.y + 1));
        dv.z = rsqrtf((float)(run.z + 1));
        dv.w = rsqrtf((float)(run.w + 1));
        *(float4*)&dinv[base] = dv;
    }
    int a0 = run.x, a1 = run.y, a2 = run.z, a3 = run.w;
    int s = a0 + a1 + a2 + a3;
    sm[t] = s;
    __syncthreads();
#pragma unroll
    for (int off = 1; off < 256; off <<= 1) {
        int v = (t >= off) ? sm[t - off] : 0;
        __syncthreads();
        sm[t] += v;
        __syncthreads();
    }
    int excl = sm[t] - s;
    if (base < n) {
        int4 o;
        o.x = excl;
        o.y = excl + a0;
        o.z = excl + a0 + a1;
        o.w = excl + a0 + a1 + a2;
        *(int4*)&offs[base] = o;  // block-local; consumers add bsums[node>>10]
    }
    if (t == 255) bsums[blockIdx.x] = sm[255];
}

// single-block exclusive scan of block sums (nb <= 256)
__global__ __launch_bounds__(256) void k_scan2(int* bsums, int nb)
{
    __shared__ int sm[256];
    int t = threadIdx.x;
    int s = (t < nb) ? bsums[t] : 0;
    sm[t] = s;
    __syncthreads();
#pragma unroll
    for (int off = 1; off < 256; off <<= 1) {
        int v = (t >= off) ? sm[t - off] : 0;
        __syncthreads();
        sm[t] += v;
        __syncthreads();
    }
    if (t < nb) bsums[t] = sm[t] - s;
}

// fused pos+fill: pos = offs[d] + bsums[d>>10] + base[c][d] + rank, scatter src.
// No atomics; bsums is a 392B L1-resident table.
__global__ void k_posfill(const int* __restrict__ dst, const int* __restrict__ src,
                          const int* __restrict__ offs, const int* __restrict__ bsums,
                          const int* __restrict__ cnt8, const int* __restrict__ rankp,
                          int* __restrict__ csr, int n, int e)
{
    int i = (blockIdx.x * blockDim.x + threadIdx.x) * 4;
    if (i >= e) return;
    if (i + 3 < e) {
        int4 d4 = *(const int4*)&dst[i];
        int4 rp = *(const int4*)&rankp[i];
        int4 s4 = *(const int4*)&src[i];
        int dd[4] = {d4.x, d4.y, d4.z, d4.w};
        int rr[4] = {rp.x, rp.y, rp.z, rp.w};
        int ss[4] = {s4.x, s4.y, s4.z, s4.w};
#pragma unroll
        for (int k = 0; k < 4; k++) {
            int d = dd[k];
            int c = ((unsigned)rr[k]) >> 24;
            int r = rr[k] & 0xFFFFFF;
            csr[offs[d] + bsums[d >> 10] + cnt8[(size_t)c * n + d] + r] = ss[k];
        }
    } else {
        for (int k = i; k < e; k++) {
            int d = dst[k];
            int rv = rankp[k];
            int c = ((unsigned)rv) >> 24;
            int r = rv & 0xFFFFFF;
            csr[offs[d] + bsums[d >> 10] + cnt8[(size_t)c * n + d] + r] = src[k];
        }
    }
}

// ---------------- W1 -> MFMA B-fragment layout, split bf16 hi/lo ----------------
__global__ void k_convw(const float* __restrict__ W, unsigned short* __restrict__ wfh,
                        unsigned short* __restrict__ wfl)
{
    int idx = blockIdx.x * blockDim.x + threadIdx.x;  // 16*2*64*8 = 16384
    int j     = idx & 7;
    int lane  = (idx >> 3) & 63;
    int ntile = (idx >> 9) & 1;
    int kstep = idx >> 10;
    int k    = kstep * 32 + (lane >> 4) * 8 + j;
    int ncol = ntile * 16 + (lane & 15);
    float v = W[k * HID + ncol];
    unsigned u = __builtin_bit_cast(unsigned, v);
    unsigned short h = (unsigned short)(u >> 16);  // truncate -> hi
    float hv = __builtin_bit_cast(float, u & 0xFFFF0000u);
    float rem = v - hv;
    unsigned ur = __builtin_bit_cast(unsigned, rem);
    ur += 0x7FFF + ((ur >> 16) & 1);               // RNE -> lo (once, tiny kernel)
    wfh[idx] = h;
    wfl[idx] = (unsigned short)(ur >> 16);
}

// ---------------- gemm1 (MFMA split-bf16): g1 = fp16(dinv * (x @ W1)) ----------------
__global__ __launch_bounds__(256) void k_gemm1(
    const float* __restrict__ x,
    const unsigned short* __restrict__ wfh, const unsigned short* __restrict__ wfl,
    const float* __restrict__ dinv, _Float16* __restrict__ g1, int n)
{
    const int t    = threadIdx.x;
    const int lane = t & 63;
    const int wave = t >> 6;
    const int m    = lane & 15;
    const int quad = lane >> 4;
    const int row0 = blockIdx.x * 64 + wave * 16;

    int arow = row0 + m;
    if (arow >= n) arow = n - 1;  // clamp: A row m only feeds output row m (unstored)
    const float* xp = x + (size_t)arow * N_IN + quad * 8;

    f32x4 acc0 = {0.f, 0.f, 0.f, 0.f};
    f32x4 acc1 = {0.f, 0.f, 0.f, 0.f};

    for (int ks = 0; ks < 16; ks++) {
        f32x4 xa = __builtin_nontemporal_load((const f32x4*)(xp + ks * 32));
        f32x4 xb = __builtin_nontemporal_load((const f32x4*)(xp + ks * 32 + 4));
        float xe[8] = {xa[0], xa[1], xa[2], xa[3], xb[0], xb[1], xb[2], xb[3]};
        bf16x8 ah, al;
#pragma unroll
        for (int j = 0; j < 8; j++) {
            unsigned u = __builtin_bit_cast(unsigned, xe[j]);
            ah[j] = (short)(u >> 16);                           // truncate -> hi
            float hv = __builtin_bit_cast(float, u & 0xFFFF0000u);
            float rem = xe[j] - hv;                             // exact (low bits)
            unsigned ur = __builtin_bit_cast(unsigned, rem);
            al[j] = (short)(ur >> 16);                          // truncate -> lo (err <= 2^-16 rel)
        }
        bf16x8 bh0 = *(const bf16x8*)(wfh + ((size_t)(ks * 2 + 0) * 64 + lane) * 8);
        bf16x8 bh1 = *(const bf16x8*)(wfh + ((size_t)(ks * 2 + 1) * 64 + lane) * 8);
        bf16x8 bl0 = *(const bf16x8*)(wfl + ((size_t)(ks * 2 + 0) * 64 + lane) * 8);
        bf16x8 bl1 = *(const bf16x8*)(wfl + ((size_t)(ks * 2 + 1) * 64 + lane) * 8);

        acc0 = __builtin_amdgcn_mfma_f32_16x16x32_bf16(ah, bh0, acc0, 0, 0, 0);
        acc0 = __builtin_amdgcn_mfma_f32_16x16x32_bf16(al, bh0, acc0, 0, 0, 0);
        acc0 = __builtin_amdgcn_mfma_f32_16x16x32_bf16(ah, bl0, acc0, 0, 0, 0);
        acc1 = __builtin_amdgcn_mfma_f32_16x16x32_bf16(ah, bh1, acc1, 0, 0, 0);
        acc1 = __builtin_amdgcn_mfma_f32_16x16x32_bf16(al, bh1, acc1, 0, 0, 0);
        acc1 = __builtin_amdgcn_mfma_f32_16x16x32_bf16(ah, bl1, acc1, 0, 0, 0);
    }

    // C/D: col = lane&15 (+16 for ntile1), row = quad*4 + r  [m89-verified mapping]
#pragma unroll
    for (int r = 0; r < 4; r++) {
        int row = row0 + quad * 4 + r;
        if (row < n) {
            float dv = dinv[row];
            g1[(size_t)row * HID + m]      = (_Float16)(acc0[r] * dv);
            g1[(size_t)row * HID + 16 + m] = (_Float16)(acc1[r] * dv);
        }
    }
}

// ---------------- fp16 exact-pack gather-aggregate: 16 lanes per node ----------------
// Rows are 32 fp16 = 64B: 4 lanes per row (col-slice cq = sl&3, 8 cols each),
// 4 edge-subgroups (q = sl>>2). Full 16-blocks branch-free; ONE predicated tail
// block (invalid slots -> sentinel row n = zeros).

// layer-1: p[r] = fp16(dinv[r] * relu(dinv[r]*sum + b1))
__global__ void k_agg1(const int* __restrict__ csr, const int* __restrict__ offs,
                       const int* __restrict__ bsums, const int* __restrict__ cnt,
                       const _Float16* __restrict__ g, const float* __restrict__ dinv,
                       const float* __restrict__ b1, _Float16* __restrict__ p, int n)
{
    int gid = blockIdx.x * blockDim.x + threadIdx.x;
    int r  = gid >> 4;
    int sl = gid & 15;
    if (r >= n) return;
    int s0 = offs[r] + bsums[r >> 10];
    int d  = cnt[r];
    int full = d & ~15;
    int q  = sl >> 2;
    int cq = sl & 3;
    const _Float16* gc = g + cq * 8;
    float acc[8] = {0.f, 0.f, 0.f, 0.f, 0.f, 0.f, 0.f, 0.f};
    if (q == 0) {  // self loop
        half8 v = *(const half8*)&gc[(size_t)r * HID];
#pragma unroll
        for (int j = 0; j < 8; j++) acc[j] = (float)v[j];
    }
    for (int b = 0; b < full; b += 16) {
        int s = csr[s0 + b + sl];
#pragma unroll
        for (int tt = 0; tt < 4; tt++) {
            int sj = __shfl(s, tt * 4 + q, 16);
            half8 v = *(const half8*)&gc[(size_t)sj * HID];
#pragma unroll
            for (int j = 0; j < 8; j++) acc[j] += (float)v[j];
        }
    }
    int rem = d - full;
    if (rem) {  // predicated tail block
        int s = (sl < rem) ? csr[s0 + full + sl] : n;
#pragma unroll
        for (int tt = 0; tt < 4; tt++) {
            int sj = __shfl(s, tt * 4 + q, 16);
            half8 v = *(const half8*)&gc[(size_t)sj * HID];
#pragma unroll
            for (int j = 0; j < 8; j++) acc[j] += (float)v[j];
        }
    }
    // butterfly-sum the 4 quarters (width 16): xor 4 then xor 8
#pragma unroll
    for (int j = 0; j < 8; j++) {
        acc[j] += __shfl(acc[j], sl ^ 4, 16);
        acc[j] += __shfl(acc[j], sl ^ 8, 16);
    }
    if (q == 0) {
        float dv = dinv[r];
        float4 ba = *(const float4*)&b1[cq * 8];
        float4 bb = *(const float4*)&b1[cq * 8 + 4];
        float bv[8] = {ba.x, ba.y, ba.z, ba.w, bb.x, bb.y, bb.z, bb.w};
        half8 hp;
#pragma unroll
        for (int j = 0; j < 8; j++)
            hp[j] = (_Float16)(dv * fmaxf(acc[j] * dv + bv[j], 0.f));
        *(half8*)&p[(size_t)r * HID + cq * 8] = hp;
    }
}

// layer-2 aggregation + output GEMM fused
__global__ void k_agg2_out(const int* __restrict__ csr, const int* __restrict__ offs,
                           const int* __restrict__ bsums, const int* __restrict__ cnt,
                           const _Float16* __restrict__ g, const float* __restrict__ dinv,
                           const float* __restrict__ W2, const float* __restrict__ b2,
                           float* __restrict__ out, int n)
{
    int gid = blockIdx.x * blockDim.x + threadIdx.x;
    int r  = gid >> 4;
    int sl = gid & 15;
    if (r >= n) return;
    int s0 = offs[r] + bsums[r >> 10];
    int d  = cnt[r];
    int full = d & ~15;
    int q  = sl >> 2;
    int cq = sl & 3;
    const _Float16* gc = g + cq * 8;
    float acc[8] = {0.f, 0.f, 0.f, 0.f, 0.f, 0.f, 0.f, 0.f};
    if (q == 0) {  // self loop
        half8 v = *(const half8*)&gc[(size_t)r * HID];
#pragma unroll
        for (int j = 0; j < 8; j++) acc[j] = (float)v[j];
    }
    for (int b = 0; b < full; b += 16) {
        int s = csr[s0 + b + sl];
#pragma unroll
        for (int tt = 0; tt < 4; tt++) {
            int sj = __shfl(s, tt * 4 + q, 16);
            half8 v = *(const half8*)&gc[(size_t)sj * HID];
#pragma unroll
            for (int j = 0; j < 8; j++) acc[j] += (float)v[j];
        }
    }
    int rem = d - full;
    if (rem) {
        int s = (sl < rem) ? csr[s0 + full + sl] : n;
#pragma unroll
        for (int tt = 0; tt < 4; tt++) {
            int sj = __shfl(s, tt * 4 + q, 16);
            half8 v = *(const half8*)&gc[(size_t)sj * HID];
#pragma unroll
            for (int j = 0; j < 8; j++) acc[j] += (float)v[j];
        }
    }
#pragma unroll
    for (int j = 0; j < 8; j++) {
        acc[j] += __shfl(acc[j], sl ^ 4, 16);
        acc[j] += __shfl(acc[j], sl ^ 8, 16);
    }
    float dv = dinv[r];
    float h[8];
#pragma unroll
    for (int j = 0; j < 8; j++) h[j] = acc[j] * dv;

    // out[r][oc..oc+3] for lanes sl<10; broadcast h[k] from lane (k>>3)
    int oc = (sl < 10) ? sl * 4 : 0;  // safe index for idle lanes
    float4 ov = *(const float4*)&b2[oc];
#pragma unroll
    for (int k = 0; k < HID; k++) {
        float a = __shfl(h[k & 7], k >> 3, 16);
        float4 wv = *(const float4*)&W2[k * OUTD + oc];
        ov.x += a * wv.x;
        ov.y += a * wv.y;
        ov.z += a * wv.z;
        ov.w += a * wv.w;
    }
    if (sl < 10) *(float4*)&out[(size_t)r * OUTD + sl * 4] = ov;
}

extern "C" void kernel_launch(void* const* d_in, const int* in_sizes, int n_in,
                              void* d_out, int out_size, void* d_ws, size_t ws_size,
                              hipStream_t stream)
{
    const float* x  = (const float*)d_in[0];
    const int*   ei = (const int*)d_in[1];
    const float* W1 = (const float*)d_in[2];
    const float* b1 = (const float*)d_in[3];
    const float* W2 = (const float*)d_in[4];
    const float* b2 = (const float*)d_in[5];
    float* out = (float*)d_out;

    const int n = in_sizes[0] / N_IN;  // 100000
    const int e = in_sizes[1] / 2;     // 1600000
    const int* src = ei;
    const int* dst = ei + e;

    char* w = (char*)d_ws;
    float* dinv   = (float*)w;            w += sizeof(float) * (size_t)((n + 3) & ~3);
    _Float16* g1  = (_Float16*)w;         w += sizeof(_Float16) * (size_t)(n + 1) * HID;
    _Float16* p   = (_Float16*)w;         w += sizeof(_Float16) * (size_t)(n + 1) * HID;
    int*   cnt    = (int*)w;              w += sizeof(int) * (size_t)((n + 3) & ~3);
    int*   offs   = (int*)w;              w += sizeof(int) * (size_t)((n + 3) & ~3);
    int*   cnt8   = (int*)w;              w += sizeof(int) * (size_t)NCOPY * ((n + 3) & ~3);
    int*   rankp  = (int*)w;              w += sizeof(int) * (size_t)((e + 3) & ~3);
    int*   bsums  = (int*)w;              w += sizeof(int) * 1024;
    unsigned short* wfh = (unsigned short*)w;  w += sizeof(unsigned short) * 16384;
    unsigned short* wfl = (unsigned short*)w;  w += sizeof(unsigned short) * 16384;
    int*   csr    = (int*)w;              w += sizeof(int) * (size_t)((e + 3) & ~3);

    const int nb = (n + 1023) / 1024;      // 98 blocks for scanA / scan2
    const int ec = (e + 3) / 4;            // 4 edges/thread for count/posfill
    const int n8_4 = (NCOPY * n + 3) / 4;  // int4 units for cnt8 zeroing

    k_init<<<(n8_4 + 255) / 256, 256, 0, stream>>>(cnt8, n8_4, n, g1, p);
    k_count<<<(ec + 255) / 256, 256, 0, stream>>>(dst, cnt8, rankp, n, e);
    k_scanA<<<nb, 256, 0, stream>>>(cnt8, cnt, dinv, offs, bsums, n);
    k_scan2<<<1, 256, 0, stream>>>(bsums, nb);
    k_posfill<<<(ec + 255) / 256, 256, 0, stream>>>(dst, src, offs, bsums, cnt8, rankp, csr, n, e);

    k_convw<<<64, 256, 0, stream>>>(W1, wfh, wfl);

    k_gemm1<<<(n + 63) / 64, 256, 0, stream>>>(x, wfh, wfl, dinv, g1, n);

    int t16 = n * 16;
    k_agg1<<<(t16 + 255) / 256, 256, 0, stream>>>(csr, offs, bsums, cnt, g1, dinv, b1, p, n);
    k_agg2_out<<<(t16 + 255) / 256, 256, 0, stream>>>(csr, offs, bsums, cnt, p, dinv, W2, b2, out, n);
}

// Round 19
// 479.515 us; speedup vs baseline: 1.0147x; 1.0147x over previous
//
#include <hip/hip_runtime.h>
#include <hip/hip_bf16.h>

#define N_IN 512
#define HID 32
#define OUTD 40
#define NCOPY 8  // per-XCD histogram copies (16 measured neutral-to-worse: extra cnt8 traffic)

typedef __attribute__((ext_vector_type(8))) short bf16x8;
typedef __attribute__((ext_vector_type(4))) float f32x4;
typedef __attribute__((ext_vector_type(8))) _Float16 half8;

// ---------------- init: cnt8 zero + zero rows g1[n], p[n] + W1 fragment build ----------------
// Blocks 0..63 additionally convert W1 into the MFMA B-fragment layout (16384 threads).

__global__ void k_init(int* __restrict__ cnt8, int n8_4, int n,
                       _Float16* __restrict__ g1, _Float16* __restrict__ p,
                       const float* __restrict__ W, unsigned short* __restrict__ wfh,
                       unsigned short* __restrict__ wfl)
{
    int i = blockIdx.x * blockDim.x + threadIdx.x;
    if (i < n8_4) {
        int4 z4 = make_int4(0, 0, 0, 0);
        *(int4*)&cnt8[(size_t)i * 4] = z4;
    }
    if (blockIdx.x == 0) {
        float4 z = make_float4(0.f, 0.f, 0.f, 0.f);
        if (threadIdx.x < 4)
            ((float4*)&g1[(size_t)n * HID])[threadIdx.x] = z;       // 64B zero row
        else if (threadIdx.x < 8)
            ((float4*)&p[(size_t)n * HID])[threadIdx.x - 4] = z;    // 64B zero row
    }
    if (i < 16384) {  // W1 -> split-bf16 fragments: idx = ((kstep*2+ntile)*64+lane)*8+j
        int j     = i & 7;
        int lane  = (i >> 3) & 63;
        int ntile = (i >> 9) & 1;
        int kstep = i >> 10;
        int k    = kstep * 32 + (lane >> 4) * 8 + j;
        int ncol = ntile * 16 + (lane & 15);
        float v = W[k * HID + ncol];
        unsigned u = __builtin_bit_cast(unsigned, v);
        unsigned short h = (unsigned short)(u >> 16);  // truncate -> hi
        float hv = __builtin_bit_cast(float, u & 0xFFFF0000u);
        float rem = v - hv;
        unsigned ur = __builtin_bit_cast(unsigned, rem);
        ur += 0x7FFF + ((ur >> 16) & 1);               // RNE -> lo
        wfh[i] = h;
        wfl[i] = (unsigned short)(ur >> 16);
    }
}

// count into per-XCD copy; emit packed (copy<<24)|rank per edge (rank <= e < 2^24)
__global__ void k_count(const int* __restrict__ dst, int* __restrict__ cnt8,
                        int* __restrict__ rankp, int n, int e)
{
    int c = blockIdx.x & (NCOPY - 1);
    int* mycnt = cnt8 + (size_t)c * n;
    int i = (blockIdx.x * blockDim.x + threadIdx.x) * 4;
    if (i + 3 < e) {
        int4 d4 = *(const int4*)&dst[i];
        int r0 = atomicAdd(&mycnt[d4.x], 1);
        int r1 = atomicAdd(&mycnt[d4.y], 1);
        int r2 = atomicAdd(&mycnt[d4.z], 1);
        int r3 = atomicAdd(&mycnt[d4.w], 1);
        int hc = c << 24;
        *(int4*)&rankp[i] = make_int4(hc | r0, hc | r1, hc | r2, hc | r3);
    } else if (i < e) {
        for (int k = i; k < e; k++) {
            int r = atomicAdd(&mycnt[dst[k]], 1);
            rankp[k] = (c << 24) | r;
        }
    }
}

// fused: per-node prefix over the NCOPY copies (bases, in place) + cnt + dinv +
// block-local exclusive scan of EXACT degrees (1024 nodes/block)
__global__ __launch_bounds__(256) void k_scanA(int* __restrict__ cnt8,
                                               int* __restrict__ cnt,
                                               float* __restrict__ dinv,
                                               int* __restrict__ offs,
                                               int* __restrict__ bsums, int n)
{
    __shared__ int sm[256];
    int t = threadIdx.x;
    int base = blockIdx.x * 1024 + t * 4;
    int4 run = make_int4(0, 0, 0, 0);
    if (base < n) {  // n % 4 == 0: all 4 valid together
#pragma unroll
        for (int c = 0; c < NCOPY; c++) {
            int4 v = *(int4*)&cnt8[(size_t)c * n + base];
            *(int4*)&cnt8[(size_t)c * n + base] = run;  // exclusive base for copy c
            run.x += v.x; run.y += v.y; run.z += v.z; run.w += v.w;
        }
        *(int4*)&cnt[base] = run;
        float4 dv;
        dv.x = rsqrtf((float)(run.x + 1));
        dv.y = rsqrtf((float)(run.y + 1));
        dv.z = rsqrtf((float)(run.z + 1));
        dv.w = rsqrtf((float)(run.w + 1));
        *(float4*)&dinv[base] = dv;
    }
    int a0 = run.x, a1 = run.y, a2 = run.z, a3 = run.w;
    int s = a0 + a1 + a2 + a3;
    sm[t] = s;
    __syncthreads();
#pragma unroll
    for (int off = 1; off < 256; off <<= 1) {
        int v = (t >= off) ? sm[t - off] : 0;
        __syncthreads();
        sm[t] += v;
        __syncthreads();
    }
    int excl = sm[t] - s;
    if (base < n) {
        int4 o;
        o.x = excl;
        o.y = excl + a0;
        o.z = excl + a0 + a1;
        o.w = excl + a0 + a1 + a2;
        *(int4*)&offs[base] = o;  // block-local; consumers add bsums[node>>10]
    }
    if (t == 255) bsums[blockIdx.x] = sm[255];
}

// single-block exclusive scan of block sums (nb <= 256)
__global__ __launch_bounds__(256) void k_scan2(int* bsums, int nb)
{
    __shared__ int sm[256];
    int t = threadIdx.x;
    int s = (t < nb) ? bsums[t] : 0;
    sm[t] = s;
    __syncthreads();
#pragma unroll
    for (int off = 1; off < 256; off <<= 1) {
        int v = (t >= off) ? sm[t - off] : 0;
        __syncthreads();
        sm[t] += v;
        __syncthreads();
    }
    if (t < nb) bsums[t] = sm[t] - s;
}

// fused pos+fill: pos = offs[d] + bsums[d>>10] + base[c][d] + rank, scatter src.
// No atomics; bsums is a 392B L1-resident table.
__global__ void k_posfill(const int* __restrict__ dst, const int* __restrict__ src,
                          const int* __restrict__ offs, const int* __restrict__ bsums,
                          const int* __restrict__ cnt8, const int* __restrict__ rankp,
                          int* __restrict__ csr, int n, int e)
{
    int i = (blockIdx.x * blockDim.x + threadIdx.x) * 4;
    if (i >= e) return;
    if (i + 3 < e) {
        int4 d4 = *(const int4*)&dst[i];
        int4 rp = *(const int4*)&rankp[i];
        int4 s4 = *(const int4*)&src[i];
        int dd[4] = {d4.x, d4.y, d4.z, d4.w};
        int rr[4] = {rp.x, rp.y, rp.z, rp.w};
        int ss[4] = {s4.x, s4.y, s4.z, s4.w};
#pragma unroll
        for (int k = 0; k < 4; k++) {
            int d = dd[k];
            int c = ((unsigned)rr[k]) >> 24;
            int r = rr[k] & 0xFFFFFF;
            csr[offs[d] + bsums[d >> 10] + cnt8[(size_t)c * n + d] + r] = ss[k];
        }
    } else {
        for (int k = i; k < e; k++) {
            int d = dst[k];
            int rv = rankp[k];
            int c = ((unsigned)rv) >> 24;
            int r = rv & 0xFFFFFF;
            csr[offs[d] + bsums[d >> 10] + cnt8[(size_t)c * n + d] + r] = src[k];
        }
    }
}

// ---------------- gemm1 (MFMA split-bf16): g1 = fp16(dinv * (x @ W1)) ----------------
__global__ __launch_bounds__(256) void k_gemm1(
    const float* __restrict__ x,
    const unsigned short* __restrict__ wfh, const unsigned short* __restrict__ wfl,
    const float* __restrict__ dinv, _Float16* __restrict__ g1, int n)
{
    const int t    = threadIdx.x;
    const int lane = t & 63;
    const int wave = t >> 6;
    const int m    = lane & 15;
    const int quad = lane >> 4;
    const int row0 = blockIdx.x * 64 + wave * 16;

    int arow = row0 + m;
    if (arow >= n) arow = n - 1;  // clamp: A row m only feeds output row m (unstored)
    const float* xp = x + (size_t)arow * N_IN + quad * 8;

    f32x4 acc0 = {0.f, 0.f, 0.f, 0.f};
    f32x4 acc1 = {0.f, 0.f, 0.f, 0.f};

    for (int ks = 0; ks < 16; ks++) {
        f32x4 xa = __builtin_nontemporal_load((const f32x4*)(xp + ks * 32));
        f32x4 xb = __builtin_nontemporal_load((const f32x4*)(xp + ks * 32 + 4));
        float xe[8] = {xa[0], xa[1], xa[2], xa[3], xb[0], xb[1], xb[2], xb[3]};
        bf16x8 ah, al;
#pragma unroll
        for (int j = 0; j < 8; j++) {
            unsigned u = __builtin_bit_cast(unsigned, xe[j]);
            ah[j] = (short)(u >> 16);                           // truncate -> hi
            float hv = __builtin_bit_cast(float, u & 0xFFFF0000u);
            float rem = xe[j] - hv;                             // exact (low bits)
            unsigned ur = __builtin_bit_cast(unsigned, rem);
            al[j] = (short)(ur >> 16);                          // truncate -> lo (err <= 2^-16 rel)
        }
        bf16x8 bh0 = *(const bf16x8*)(wfh + ((size_t)(ks * 2 + 0) * 64 + lane) * 8);
        bf16x8 bh1 = *(const bf16x8*)(wfh + ((size_t)(ks * 2 + 1) * 64 + lane) * 8);
        bf16x8 bl0 = *(const bf16x8*)(wfl + ((size_t)(ks * 2 + 0) * 64 + lane) * 8);
        bf16x8 bl1 = *(const bf16x8*)(wfl + ((size_t)(ks * 2 + 1) * 64 + lane) * 8);

        acc0 = __builtin_amdgcn_mfma_f32_16x16x32_bf16(ah, bh0, acc0, 0, 0, 0);
        acc0 = __builtin_amdgcn_mfma_f32_16x16x32_bf16(al, bh0, acc0, 0, 0, 0);
        acc0 = __builtin_amdgcn_mfma_f32_16x16x32_bf16(ah, bl0, acc0, 0, 0, 0);
        acc1 = __builtin_amdgcn_mfma_f32_16x16x32_bf16(ah, bh1, acc1, 0, 0, 0);
        acc1 = __builtin_amdgcn_mfma_f32_16x16x32_bf16(al, bh1, acc1, 0, 0, 0);
        acc1 = __builtin_amdgcn_mfma_f32_16x16x32_bf16(ah, bl1, acc1, 0, 0, 0);
    }

    // C/D: col = lane&15 (+16 for ntile1), row = quad*4 + r  [m89-verified mapping]
#pragma unroll
    for (int r = 0; r < 4; r++) {
        int row = row0 + quad * 4 + r;
        if (row < n) {
            float dv = dinv[row];
            g1[(size_t)row * HID + m]      = (_Float16)(acc0[r] * dv);
            g1[(size_t)row * HID + 16 + m] = (_Float16)(acc1[r] * dv);
        }
    }
}

// ---------------- fp16 exact-pack gather-aggregate: 16 lanes per node ----------------
// Rows are 32 fp16 = 64B: 4 lanes per row (col-slice cq = sl&3, 8 cols each),
// 4 edge-subgroups (q = sl>>2). Full 16-blocks branch-free; ONE predicated tail
// block (invalid slots -> sentinel row n = zeros).

// layer-1: p[r] = fp16(dinv[r] * relu(dinv[r]*sum + b1))
__global__ void k_agg1(const int* __restrict__ csr, const int* __restrict__ offs,
                       const int* __restrict__ bsums, const int* __restrict__ cnt,
                       const _Float16* __restrict__ g, const float* __restrict__ dinv,
                       const float* __restrict__ b1, _Float16* __restrict__ p, int n)
{
    int gid = blockIdx.x * blockDim.x + threadIdx.x;
    int r  = gid >> 4;
    int sl = gid & 15;
    if (r >= n) return;
    int s0 = offs[r] + bsums[r >> 10];
    int d  = cnt[r];
    int full = d & ~15;
    int q  = sl >> 2;
    int cq = sl & 3;
    const _Float16* gc = g + cq * 8;
    float acc[8] = {0.f, 0.f, 0.f, 0.f, 0.f, 0.f, 0.f, 0.f};
    if (q == 0) {  // self loop
        half8 v = *(const half8*)&gc[(size_t)r * HID];
#pragma unroll
        for (int j = 0; j < 8; j++) acc[j] = (float)v[j];
    }
    for (int b = 0; b < full; b += 16) {
        int s = csr[s0 + b + sl];
#pragma unroll
        for (int tt = 0; tt < 4; tt++) {
            int sj = __shfl(s, tt * 4 + q, 16);
            half8 v = *(const half8*)&gc[(size_t)sj * HID];
#pragma unroll
            for (int j = 0; j < 8; j++) acc[j] += (float)v[j];
        }
    }
    int rem = d - full;
    if (rem) {  // predicated tail block
        int s = (sl < rem) ? csr[s0 + full + sl] : n;
#pragma unroll
        for (int tt = 0; tt < 4; tt++) {
            int sj = __shfl(s, tt * 4 + q, 16);
            half8 v = *(const half8*)&gc[(size_t)sj * HID];
#pragma unroll
            for (int j = 0; j < 8; j++) acc[j] += (float)v[j];
        }
    }
    // butterfly-sum the 4 quarters (width 16): xor 4 then xor 8
#pragma unroll
    for (int j = 0; j < 8; j++) {
        acc[j] += __shfl(acc[j], sl ^ 4, 16);
        acc[j] += __shfl(acc[j], sl ^ 8, 16);
    }
    if (q == 0) {
        float dv = dinv[r];
        float4 ba = *(const float4*)&b1[cq * 8];
        float4 bb = *(const float4*)&b1[cq * 8 + 4];
        float bv[8] = {ba.x, ba.y, ba.z, ba.w, bb.x, bb.y, bb.z, bb.w};
        half8 hp;
#pragma unroll
        for (int j = 0; j < 8; j++)
            hp[j] = (_Float16)(dv * fmaxf(acc[j] * dv + bv[j], 0.f));
        *(half8*)&p[(size_t)r * HID + cq * 8] = hp;
    }
}

// layer-2 aggregation + output GEMM fused
__global__ void k_agg2_out(const int* __restrict__ csr, const int* __restrict__ offs,
                           const int* __restrict__ bsums, const int* __restrict__ cnt,
                           const _Float16* __restrict__ g, const float* __restrict__ dinv,
                           const float* __restrict__ W2, const float* __restrict__ b2,
                           float* __restrict__ out, int n)
{
    int gid = blockIdx.x * blockDim.x + threadIdx.x;
    int r  = gid >> 4;
    int sl = gid & 15;
    if (r >= n) return;
    int s0 = offs[r] + bsums[r >> 10];
    int d  = cnt[r];
    int full = d & ~15;
    int q  = sl >> 2;
    int cq = sl & 3;
    const _Float16* gc = g + cq * 8;
    float acc[8] = {0.f, 0.f, 0.f, 0.f, 0.f, 0.f, 0.f, 0.f};
    if (q == 0) {  // self loop
        half8 v = *(const half8*)&gc[(size_t)r * HID];
#pragma unroll
        for (int j = 0; j < 8; j++) acc[j] = (float)v[j];
    }
    for (int b = 0; b < full; b += 16) {
        int s = csr[s0 + b + sl];
#pragma unroll
        for (int tt = 0; tt < 4; tt++) {
            int sj = __shfl(s, tt * 4 + q, 16);
            half8 v = *(const half8*)&gc[(size_t)sj * HID];
#pragma unroll
            for (int j = 0; j < 8; j++) acc[j] += (float)v[j];
        }
    }
    int rem = d - full;
    if (rem) {
        int s = (sl < rem) ? csr[s0 + full + sl] : n;
#pragma unroll
        for (int tt = 0; tt < 4; tt++) {
            int sj = __shfl(s, tt * 4 + q, 16);
            half8 v = *(const half8*)&gc[(size_t)sj * HID];
#pragma unroll
            for (int j = 0; j < 8; j++) acc[j] += (float)v[j];
        }
    }
#pragma unroll
    for (int j = 0; j < 8; j++) {
        acc[j] += __shfl(acc[j], sl ^ 4, 16);
        acc[j] += __shfl(acc[j], sl ^ 8, 16);
    }
    float dv = dinv[r];
    float h[8];
#pragma unroll
    for (int j = 0; j < 8; j++) h[j] = acc[j] * dv;

    // out[r][oc..oc+3] for lanes sl<10; broadcast h[k] from lane (k>>3)
    int oc = (sl < 10) ? sl * 4 : 0;  // safe index for idle lanes
    float4 ov = *(const float4*)&b2[oc];
#pragma unroll
    for (int k = 0; k < HID; k++) {
        float a = __shfl(h[k & 7], k >> 3, 16);
        float4 wv = *(const float4*)&W2[k * OUTD + oc];
        ov.x += a * wv.x;
        ov.y += a * wv.y;
        ov.z += a * wv.z;
        ov.w += a * wv.w;
    }
    if (sl < 10) *(float4*)&out[(size_t)r * OUTD + sl * 4] = ov;
}

extern "C" void kernel_launch(void* const* d_in, const int* in_sizes, int n_in,
                              void* d_out, int out_size, void* d_ws, size_t ws_size,
                              hipStream_t stream)
{
    const float* x  = (const float*)d_in[0];
    const int*   ei = (const int*)d_in[1];
    const float* W1 = (const float*)d_in[2];
    const float* b1 = (const float*)d_in[3];
    const float* W2 = (const float*)d_in[4];
    const float* b2 = (const float*)d_in[5];
    float* out = (float*)d_out;

    const int n = in_sizes[0] / N_IN;  // 100000
    const int e = in_sizes[1] / 2;     // 1600000
    const int* src = ei;
    const int* dst = ei + e;

    char* w = (char*)d_ws;
    float* dinv   = (float*)w;            w += sizeof(float) * (size_t)((n + 3) & ~3);
    _Float16* g1  = (_Float16*)w;         w += sizeof(_Float16) * (size_t)(n + 1) * HID;
    _Float16* p   = (_Float16*)w;         w += sizeof(_Float16) * (size_t)(n + 1) * HID;
    int*   cnt    = (int*)w;              w += sizeof(int) * (size_t)((n + 3) & ~3);
    int*   offs   = (int*)w;              w += sizeof(int) * (size_t)((n + 3) & ~3);
    int*   cnt8   = (int*)w;              w += sizeof(int) * (size_t)NCOPY * ((n + 3) & ~3);
    int*   rankp  = (int*)w;              w += sizeof(int) * (size_t)((e + 3) & ~3);
    int*   bsums  = (int*)w;              w += sizeof(int) * 1024;
    unsigned short* wfh = (unsigned short*)w;  w += sizeof(unsigned short) * 16384;
    unsigned short* wfl = (unsigned short*)w;  w += sizeof(unsigned short) * 16384;
    int*   csr    = (int*)w;              w += sizeof(int) * (size_t)((e + 3) & ~3);

    const int nb = (n + 1023) / 1024;      // 98 blocks for scanA / scan2
    const int ec = (e + 3) / 4;            // 4 edges/thread for count/posfill
    const int n8_4 = (NCOPY * n + 3) / 4;  // int4 units for cnt8 zeroing

    k_init<<<(n8_4 + 255) / 256, 256, 0, stream>>>(cnt8, n8_4, n, g1, p, W1, wfh, wfl);
    k_count<<<(ec + 255) / 256, 256, 0, stream>>>(dst, cnt8, rankp, n, e);
    k_scanA<<<nb, 256, 0, stream>>>(cnt8, cnt, dinv, offs, bsums, n);
    k_scan2<<<1, 256, 0, stream>>>(bsums, nb);
    k_posfill<<<(ec + 255) / 256, 256, 0, stream>>>(dst, src, offs, bsums, cnt8, rankp, csr, n, e);

    k_gemm1<<<(n + 63) / 64, 256, 0, stream>>>(x, wfh, wfl, dinv, g1, n);

    int t16 = n * 16;
    k_agg1<<<(t16 + 255) / 256, 256, 0, stream>>>(csr, offs, bsums, cnt, g1, dinv, b1, p, n);
    k_agg2_out<<<(t16 + 255) / 256, 256, 0, stream>>>(csr, offs, bsums, cnt, p, dinv, W2, b2, out, n);
}